// Round 4
// baseline (213.905 us; speedup 1.0000x reference)
//
#include <hip/hip_runtime.h>
#include <math.h>

#define G      26
#define NA     5
#define NC     20
#define NB     128
#define NT     1024
#define GG     (G*G)            // 676
#define CELLS  (NB*NA*GG)       // 432640
#define CH     (NC+5)           // 25
#define NBLK   (CELLS/256)      // 1690 (exact)
#define IGNORE_THRESH 0.6f
#define OBJ_SCALE   5.0f
#define NOOBJ_SCALE 1.0f
#define CLS_SCALE   1.0f
#define COORD_SCALE 1.0f
#define STRIDE_F    32.0f

__device__ __constant__ float c_aw[NA] = {1.08f, 3.42f, 6.63f, 9.42f, 16.62f};
__device__ __constant__ float c_ah[NA] = {1.19f, 4.41f, 11.38f, 5.11f, 10.52f};

__device__ __forceinline__ float sigmoidf(float v) {
    return 1.0f / (1.0f + expf(-v));
}

// -------- Pass 1: parallel target resolution (1 wave per target) --------
// 256 blocks x 256 threads. Each block redundantly packs all NT targets into
// LDS (L2-hot), then its 4 waves each resolve one target via a 16-entry-per-
// lane scan + OR shuffle-reduce. Deterministic output slots (-1 sentinels).
__launch_bounds__(256)
__global__ void k_resolve(const float* __restrict__ tg,
                          float* __restrict__ acc,
                          int2* __restrict__ obj_list,
                          int* __restrict__ supp_list) {
    __shared__ int packed[NT];
    int tid = threadIdx.x;
    if (blockIdx.x == 0 && tid < 16) acc[tid] = 0.0f;   // also zeroes ctr @ acc[12]

    #pragma unroll
    for (int q = 0; q < 4; ++q) {
        int t = tid + q * 256;
        int   b  = (int)tg[t * 6 + 0];
        float cx = tg[t * 6 + 2] * (float)G;
        float cy = tg[t * 6 + 3] * (float)G;
        float gw = tg[t * 6 + 4] * (float)G;
        float gh = tg[t * 6 + 5] * (float)G;
        int gi = (int)floorf(cx);
        int gj = (int)floorf(cy);
        float best = -1.0f;
        int bn = 0, bits = 0;
        #pragma unroll
        for (int a = 0; a < NA; ++a) {
            float inter = fminf(c_aw[a], gw) * fminf(c_ah[a], gh);
            float uni   = c_aw[a] * c_ah[a] + 1e-16f + gw * gh - inter;
            float iou   = inter / uni;
            if (iou > best) { best = iou; bn = a; }      // first max wins (jnp.argmax)
            if (iou > IGNORE_THRESH) bits |= (1 << a);
        }
        int key = (b * G + gj) * G + gi;                 // < 86528, fits 17 bits
        packed[t] = (key << 8) | (bn << 5) | bits;
    }
    __syncthreads();

    int t    = blockIdx.x * 4 + (tid >> 6);              // wave -> target
    int lane = tid & 63;
    int me     = packed[t];
    int mykey  = me >> 8;
    int mybn   = (me >> 5) & 7;
    int mybits = me & 31;

    // agg: bits0-4 used anchors, bits5-9 earlier supp bits, bit10 not-winner
    int agg = 0;
    #pragma unroll
    for (int s = 0; s < 16; ++s) {
        int o  = lane + s * 64;
        int pv = packed[o];
        if ((pv >> 8) == mykey) {
            int obn = (pv >> 5) & 7;
            agg |= (1 << obn);                           // used
            if (o > t && obn == mybn) agg |= (1 << 10);  // later target owns cell
            if (o < t) agg |= (pv & 31) << 5;            // earlier supp rep
        }
    }
    #pragma unroll
    for (int off = 32; off > 0; off >>= 1) agg |= __shfl_xor(agg, off);

    if (lane == 0) {
        int used    = agg & 31;
        int earlier = (agg >> 5) & 31;
        bool winner = !(agg & (1 << 10));
        int cell0 = (mykey / GG) * (NA * GG) + (mykey % GG);
        obj_list[t] = winner ? make_int2(cell0 + mybn * GG, t) : make_int2(-1, -1);
        #pragma unroll
        for (int a = 0; a < NA; ++a) {
            bool s = (mybits >> a & 1) && !(earlier >> a & 1) && !(used >> a & 1);
            supp_list[t * NA + a] = s ? (cell0 + a * GG) : -1;
        }
    }
}

// -------- Pass 2: streaming elementwise + inline loss + fused finalize --------
// Per block: build a 256-entry LDS status map from the compact lists (L2-hot),
// then each thread fully handles its own cell. Last block finalizes the loss.
__launch_bounds__(256)
__global__ void k_main(const float* __restrict__ x,
                       const float* __restrict__ tg,
                       const int2* __restrict__ obj_list,
                       const int* __restrict__ supp_list,
                       float* __restrict__ out,
                       float* __restrict__ acc,
                       float* __restrict__ loss_out) {
    __shared__ float stage[256 * CH];   // 25600 B
    __shared__ int   lmap[256];         // -1 plain / -2 supp / >=0 obj target
    __shared__ float red[4][9];
    __shared__ int   s_last;

    int tid  = threadIdx.x;
    int base = blockIdx.x * 256;

    lmap[tid] = -1;
    __syncthreads();
    #pragma unroll
    for (int k = 0; k < 4; ++k) {                        // 1024 obj slots
        int2 e = obj_list[tid + k * 256];
        unsigned d = (unsigned)(e.x - base);
        if (d < 256u) lmap[d] = e.y;                     // e.x==-1 wraps huge
    }
    #pragma unroll
    for (int k = 0; k < 20; ++k) {                       // 5120 supp slots
        int c = supp_list[tid + k * 256];
        unsigned d = (unsigned)(c - base);
        if (d < 256u) lmap[d] = -2;                      // disjoint from obj cells
    }

    int cell = base + tid;
    int sp = cell % GG;
    int pa = cell / GG;                                  // b*NA + a
    int a  = pa % NA;
    int i  = sp % G, j = sp / G;

    const float* xp = x + (size_t)pa * (CH * GG) + sp;
    float v[CH];
    #pragma unroll
    for (int c = 0; c < CH; ++c) v[c] = xp[(size_t)c * GG];

    float px = sigmoidf(v[0]);
    float py = sigmoidf(v[1]);
    float pconf = sigmoidf(v[4]);
    float bx = px + (float)i;
    float by = py + (float)j;
    float bw = expf(v[2]) * c_aw[a];
    float bh = expf(v[3]) * c_ah[a];

    float* s = &stage[tid * CH];                         // stride 25 (odd): 2-way, free
    s[0] = bx * STRIDE_F;
    s[1] = by * STRIDE_F;
    s[2] = bw * STRIDE_F;
    s[3] = bh * STRIDE_F;
    s[4] = pconf;
    float pcls[NC];
    #pragma unroll
    for (int c = 0; c < NC; ++c) { pcls[c] = sigmoidf(v[5 + c]); s[5 + c] = pcls[c]; }

    __syncthreads();                                     // lmap + stage ready

    // coalesced float4 copy-out: 1600 float4 per block
    float4* ob = (float4*)(out + (size_t)blockIdx.x * (256 * CH));
    const float4* st = (const float4*)stage;
    #pragma unroll
    for (int k = 0; k < 6; ++k) ob[k * 256 + tid] = st[k * 256 + tid];
    if (tid < 64) ob[1536 + tid] = st[1536 + tid];

    // per-cell loss terms: {sx, sy, sw, sh, conf_obj, conf_noobj, cls, n_obj, n_noobj}
    float p[9];
    #pragma unroll
    for (int q = 0; q < 9; ++q) p[q] = 0.0f;

    int m = lmap[tid];
    if (m == -1) {                                       // plain noobj cell
        p[5] = pconf * pconf;                            // tconf == 0 here
        p[8] = 1.0f;
    } else if (m >= 0) {                                 // obj cell, target m
        float cx = tg[m * 6 + 2] * (float)G;
        float cy = tg[m * 6 + 3] * (float)G;
        float gw = tg[m * 6 + 4] * (float)G;
        float gh = tg[m * 6 + 5] * (float)G;
        int label = (int)tg[m * 6 + 1];
        float tx = cx - floorf(cx);
        float ty = cy - floorf(cy);
        float tw = logf(gw / c_aw[a] + 1e-16f);
        float th = logf(gh / c_ah[a] + 1e-16f);

        float b1x1 = bx - bw * 0.5f, b1x2 = bx + bw * 0.5f;
        float b1y1 = by - bh * 0.5f, b1y2 = by + bh * 0.5f;
        float b2x1 = cx - gw * 0.5f, b2x2 = cx + gw * 0.5f;
        float b2y1 = cy - gh * 0.5f, b2y2 = cy + gh * 0.5f;
        float iw = fmaxf(fminf(b1x2, b2x2) - fmaxf(b1x1, b2x1) + 1.0f, 0.0f);
        float ih = fmaxf(fminf(b1y2, b2y2) - fmaxf(b1y1, b2y1) + 1.0f, 0.0f);
        float inter = iw * ih;
        float a1 = (b1x2 - b1x1 + 1.0f) * (b1y2 - b1y1 + 1.0f);
        float a2 = (b2x2 - b2x1 + 1.0f) * (b2y2 - b2y1 + 1.0f);
        float iou = inter / (a1 + a2 - inter + 1e-16f);

        p[0] = (px - tx) * (px - tx);
        p[1] = (py - ty) * (py - ty);
        p[2] = (v[2] - tw) * (v[2] - tw);
        p[3] = (v[3] - th) * (v[3] - th);
        p[4] = (pconf - iou) * (pconf - iou);
        float cls = 0.0f;
        #pragma unroll
        for (int c = 0; c < NC; ++c) {
            float pc = fminf(fmaxf(pcls[c], 1e-12f), 1.0f - 1e-12f);
            float tc = (c == label) ? 1.0f : 0.0f;
            cls -= tc * logf(pc) + (1.0f - tc) * logf(1.0f - pc);
        }
        p[6] = cls;
        p[7] = 1.0f;
    }                                                    // m == -2: suppressed, nothing

    #pragma unroll
    for (int o = 32; o > 0; o >>= 1) {
        #pragma unroll
        for (int q = 0; q < 9; ++q) p[q] += __shfl_down(p[q], o);
    }
    int lane = tid & 63, wid = tid >> 6;
    if (lane == 0) {
        #pragma unroll
        for (int q = 0; q < 9; ++q) red[wid][q] = p[q];
    }
    __syncthreads();
    if (tid < 9) {
        float sum = red[0][tid] + red[1][tid] + red[2][tid] + red[3][tid];
        if (sum != 0.0f) atomicAdd(&acc[tid], sum);
    }

    // fused finalize: last block to finish computes the scalar loss
    __threadfence();                                     // make acc adds visible
    __syncthreads();
    if (tid == 0) {
        unsigned old = atomicAdd((unsigned*)&acc[12], 1u);
        s_last = (old == (unsigned)(gridDim.x - 1)) ? 1 : 0;
    }
    __syncthreads();
    if (s_last && tid == 0) {
        float sv[9];
        #pragma unroll
        for (int q = 0; q < 9; ++q) sv[q] = atomicAdd(&acc[q], 0.0f);  // coherent read
        float n_obj   = sv[7];
        float n_noobj = sv[8];
        float l = COORD_SCALE * (sv[0] + sv[1] + sv[2] + sv[3]) / n_obj
                + OBJ_SCALE * sv[4] / n_obj
                + NOOBJ_SCALE * sv[5] / n_noobj
                + CLS_SCALE * sv[6] / (n_obj * (float)NC);
        *loss_out = l;
    }
}

extern "C" void kernel_launch(void* const* d_in, const int* in_sizes, int n_in,
                              void* d_out, int out_size, void* d_ws, size_t ws_size,
                              hipStream_t stream) {
    const float* x  = (const float*)d_in[0];
    const float* tg = (const float*)d_in[1];
    float* out = (float*)d_out;

    char* ws = (char*)d_ws;
    float* acc       = (float*)ws;                   // 16 floats (ctr at [12])
    int2*  obj_list  = (int2*)(ws + 64);             // 1024 * int2 (all slots written)
    int*   supp_list = (int*)(ws + 64 + NT * 8);     // 5120 ints  (all slots written)

    k_resolve<<<NT / 4, 256, 0, stream>>>(tg, acc, obj_list, supp_list);
    k_main<<<NBLK, 256, 0, stream>>>(x, tg, obj_list, supp_list, out, acc,
                                     out + (size_t)CELLS * CH);
}

// Round 5
// 50.896 us; speedup vs baseline: 4.2028x; 4.2028x over previous
//
#include <hip/hip_runtime.h>
#include <math.h>

#define G      26
#define NA     5
#define NC     20
#define NB     128
#define NT     1024
#define GG     (G*G)            // 676
#define CELLS  (NB*NA*GG)       // 432640
#define CH     (NC+5)           // 25
#define CPB    512              // cells per block
#define NBLK   (CELLS/CPB)      // 845 (exact)
#define IGNORE_THRESH 0.6f
#define OBJ_SCALE   5.0f
#define NOOBJ_SCALE 1.0f
#define CLS_SCALE   1.0f
#define COORD_SCALE 1.0f
#define STRIDE_F    32.0f

__device__ __constant__ float c_aw[NA] = {1.08f, 3.42f, 6.63f, 9.42f, 16.62f};
__device__ __constant__ float c_ah[NA] = {1.19f, 4.41f, 11.38f, 5.11f, 10.52f};

__device__ __forceinline__ float sigmoidf(float v) {
    return 1.0f / (1.0f + expf(-v));
}

// -------- Pass 1: parallel target resolution (1 wave per target) --------
__launch_bounds__(256)
__global__ void k_resolve(const float* __restrict__ tg,
                          float* __restrict__ acc,
                          int2* __restrict__ obj_list,
                          int* __restrict__ supp_list) {
    __shared__ int packed[NT];
    int tid = threadIdx.x;
    if (blockIdx.x == 0 && tid < 16) acc[tid] = 0.0f;

    #pragma unroll
    for (int q = 0; q < 4; ++q) {
        int t = tid + q * 256;
        int   b  = (int)tg[t * 6 + 0];
        float cx = tg[t * 6 + 2] * (float)G;
        float cy = tg[t * 6 + 3] * (float)G;
        float gw = tg[t * 6 + 4] * (float)G;
        float gh = tg[t * 6 + 5] * (float)G;
        int gi = (int)floorf(cx);
        int gj = (int)floorf(cy);
        float best = -1.0f;
        int bn = 0, bits = 0;
        #pragma unroll
        for (int a = 0; a < NA; ++a) {
            float inter = fminf(c_aw[a], gw) * fminf(c_ah[a], gh);
            float uni   = c_aw[a] * c_ah[a] + 1e-16f + gw * gh - inter;
            float iou   = inter / uni;
            if (iou > best) { best = iou; bn = a; }      // first max wins (jnp.argmax)
            if (iou > IGNORE_THRESH) bits |= (1 << a);
        }
        int key = (b * G + gj) * G + gi;                 // < 86528, fits 17 bits
        packed[t] = (key << 8) | (bn << 5) | bits;
    }
    __syncthreads();

    int t    = blockIdx.x * 4 + (tid >> 6);              // wave -> target
    int lane = tid & 63;
    int me     = packed[t];
    int mykey  = me >> 8;
    int mybn   = (me >> 5) & 7;
    int mybits = me & 31;

    // agg: bits0-4 used anchors, bits5-9 earlier supp bits, bit10 not-winner
    int agg = 0;
    #pragma unroll
    for (int s = 0; s < 16; ++s) {
        int o  = lane + s * 64;
        int pv = packed[o];
        if ((pv >> 8) == mykey) {
            int obn = (pv >> 5) & 7;
            agg |= (1 << obn);                           // used
            if (o > t && obn == mybn) agg |= (1 << 10);  // later target owns cell
            if (o < t) agg |= (pv & 31) << 5;            // earlier supp rep
        }
    }
    #pragma unroll
    for (int off = 32; off > 0; off >>= 1) agg |= __shfl_xor(agg, off);

    if (lane == 0) {
        int used    = agg & 31;
        int earlier = (agg >> 5) & 31;
        bool winner = !(agg & (1 << 10));
        int cell0 = (mykey / GG) * (NA * GG) + (mykey % GG);
        obj_list[t] = winner ? make_int2(cell0 + mybn * GG, t) : make_int2(-1, -1);
        #pragma unroll
        for (int a = 0; a < NA; ++a) {
            bool s = (mybits >> a & 1) && !(earlier >> a & 1) && !(used >> a & 1);
            supp_list[t * NA + a] = s ? (cell0 + a * GG) : -1;
        }
    }
}

// -------- Pass 2: streaming elementwise + inline loss (no fences!) --------
// 2 cells/thread, float2 loads; per-block LDS status map from compact lists.
__launch_bounds__(256)
__global__ void k_main(const float* __restrict__ x,
                       const float* __restrict__ tg,
                       const int2* __restrict__ obj_list,
                       const int* __restrict__ supp_list,
                       float* __restrict__ out,
                       float* __restrict__ acc) {
    __shared__ float stage[CPB * CH];   // 51200 B
    __shared__ int   lmap[CPB];         // -1 plain / -2 supp / >=0 obj target
    __shared__ float red[4][9];

    int tid  = threadIdx.x;
    int base = blockIdx.x * CPB;

    lmap[tid] = -1;
    lmap[tid + 256] = -1;
    __syncthreads();
    #pragma unroll
    for (int k = 0; k < 4; ++k) {                        // 1024 obj slots (L2-hot)
        int2 e = obj_list[tid + k * 256];
        unsigned d = (unsigned)(e.x - base);
        if (d < (unsigned)CPB) lmap[d] = e.y;            // e.x==-1 wraps huge
    }
    #pragma unroll
    for (int k = 0; k < 20; ++k) {                       // 5120 supp slots
        int c = supp_list[tid + k * 256];
        unsigned d = (unsigned)(c - base);
        if (d < (unsigned)CPB) lmap[d] = -2;             // disjoint from obj cells
    }

    int cell0 = base + tid * 2;
    int sp = cell0 % GG;                                 // even; pair shares panel+row
    int pa = cell0 / GG;                                 // b*NA + a
    int a  = pa % NA;
    int i0 = sp % G, j0 = sp / G;
    float aw = c_aw[a], ah = c_ah[a];

    const float2* xp = (const float2*)(x + (size_t)pa * (CH * GG) + sp);
    float2 v[CH];
    #pragma unroll
    for (int c = 0; c < CH; ++c) v[c] = xp[c * (GG / 2)];

    float px0 = sigmoidf(v[0].x), px1 = sigmoidf(v[0].y);
    float py0 = sigmoidf(v[1].x), py1 = sigmoidf(v[1].y);
    float pw0 = v[2].x, pw1 = v[2].y;
    float ph0 = v[3].x, ph1 = v[3].y;
    float pc0 = sigmoidf(v[4].x), pc1 = sigmoidf(v[4].y);
    float bx0 = px0 + (float)i0,      by0 = py0 + (float)j0;
    float bx1 = px1 + (float)(i0 + 1), by1 = py1 + (float)j0;
    float bw0 = expf(pw0) * aw, bw1 = expf(pw1) * aw;
    float bh0 = expf(ph0) * ah, bh1 = expf(ph1) * ah;

    float* s = &stage[tid * 2 * CH];                     // stride 50 floats: 2-way, free
    s[0] = bx0 * STRIDE_F;  s[CH + 0] = bx1 * STRIDE_F;
    s[1] = by0 * STRIDE_F;  s[CH + 1] = by1 * STRIDE_F;
    s[2] = bw0 * STRIDE_F;  s[CH + 2] = bw1 * STRIDE_F;
    s[3] = bh0 * STRIDE_F;  s[CH + 3] = bh1 * STRIDE_F;
    s[4] = pc0;             s[CH + 4] = pc1;
    #pragma unroll
    for (int c = 0; c < NC; ++c) {
        s[5 + c]      = sigmoidf(v[5 + c].x);
        s[CH + 5 + c] = sigmoidf(v[5 + c].y);
    }

    __syncthreads();                                     // lmap + stage complete

    // coalesced float4 copy-out: 3200 float4 per block
    float4* ob = (float4*)(out + (size_t)blockIdx.x * (CPB * CH));
    const float4* st = (const float4*)stage;
    #pragma unroll
    for (int k = 0; k < 12; ++k) ob[k * 256 + tid] = st[k * 256 + tid];
    if (tid < 128) ob[3072 + tid] = st[3072 + tid];

    // per-cell loss: {sx, sy, sw, sh, conf_obj, conf_noobj, cls, n_obj, n_noobj}
    float p[9];
    #pragma unroll
    for (int q = 0; q < 9; ++q) p[q] = 0.0f;

    #pragma unroll
    for (int h = 0; h < 2; ++h) {                        // static after unroll
        int m = lmap[tid * 2 + h];
        float pconf = h ? pc1 : pc0;
        if (m == -1) {                                   // plain noobj cell
            p[5] += pconf * pconf;                       // tconf == 0 here
            p[8] += 1.0f;
        } else if (m >= 0) {                             // obj cell, target m
            float px = h ? px1 : px0,  py = h ? py1 : py0;
            float pw = h ? pw1 : pw0,  ph = h ? ph1 : ph0;
            float bx = h ? bx1 : bx0,  by = h ? by1 : by0;
            float bw = h ? bw1 : bw0,  bh = h ? bh1 : bh0;

            float cx = tg[m * 6 + 2] * (float)G;
            float cy = tg[m * 6 + 3] * (float)G;
            float gw = tg[m * 6 + 4] * (float)G;
            float gh = tg[m * 6 + 5] * (float)G;
            int label = (int)tg[m * 6 + 1];
            float tx = cx - floorf(cx);
            float ty = cy - floorf(cy);
            float tw = logf(gw / aw + 1e-16f);
            float th = logf(gh / ah + 1e-16f);

            float b1x1 = bx - bw * 0.5f, b1x2 = bx + bw * 0.5f;
            float b1y1 = by - bh * 0.5f, b1y2 = by + bh * 0.5f;
            float b2x1 = cx - gw * 0.5f, b2x2 = cx + gw * 0.5f;
            float b2y1 = cy - gh * 0.5f, b2y2 = cy + gh * 0.5f;
            float iw = fmaxf(fminf(b1x2, b2x2) - fmaxf(b1x1, b2x1) + 1.0f, 0.0f);
            float ih = fmaxf(fminf(b1y2, b2y2) - fmaxf(b1y1, b2y1) + 1.0f, 0.0f);
            float inter = iw * ih;
            float a1 = (b1x2 - b1x1 + 1.0f) * (b1y2 - b1y1 + 1.0f);
            float a2 = (b2x2 - b2x1 + 1.0f) * (b2y2 - b2y1 + 1.0f);
            float iou = inter / (a1 + a2 - inter + 1e-16f);

            p[0] += (px - tx) * (px - tx);
            p[1] += (py - ty) * (py - ty);
            p[2] += (pw - tw) * (pw - tw);
            p[3] += (ph - th) * (ph - th);
            p[4] += (pconf - iou) * (pconf - iou);
            float cls = 0.0f;
            const float* sc = s + h * CH + 5;            // own stage region
            #pragma unroll
            for (int c = 0; c < NC; ++c) {
                float pcv = fminf(fmaxf(sc[c], 1e-12f), 1.0f - 1e-12f);
                float tc = (c == label) ? 1.0f : 0.0f;
                cls -= tc * logf(pcv) + (1.0f - tc) * logf(1.0f - pcv);
            }
            p[6] += cls;
            p[7] += 1.0f;
        }                                                // m == -2: suppressed, skip
    }

    #pragma unroll
    for (int o = 32; o > 0; o >>= 1) {
        #pragma unroll
        for (int q = 0; q < 9; ++q) p[q] += __shfl_down(p[q], o);
    }
    int lane = tid & 63, wid = tid >> 6;
    if (lane == 0) {
        #pragma unroll
        for (int q = 0; q < 9; ++q) red[wid][q] = p[q];
    }
    __syncthreads();
    if (tid < 9) {
        float sum = red[0][tid] + red[1][tid] + red[2][tid] + red[3][tid];
        if (sum != 0.0f) atomicAdd(&acc[tid], sum);
    }
}

// -------- Pass 3: finalize scalar loss (kernel boundary = coherence) --------
__global__ void k_final(const float* __restrict__ acc, float* __restrict__ loss_out) {
    float n_obj   = acc[7];
    float n_noobj = acc[8];
    float l = COORD_SCALE * (acc[0] + acc[1] + acc[2] + acc[3]) / n_obj
            + OBJ_SCALE * acc[4] / n_obj
            + NOOBJ_SCALE * acc[5] / n_noobj
            + CLS_SCALE * acc[6] / (n_obj * (float)NC);
    *loss_out = l;
}

extern "C" void kernel_launch(void* const* d_in, const int* in_sizes, int n_in,
                              void* d_out, int out_size, void* d_ws, size_t ws_size,
                              hipStream_t stream) {
    const float* x  = (const float*)d_in[0];
    const float* tg = (const float*)d_in[1];
    float* out = (float*)d_out;

    char* ws = (char*)d_ws;
    float* acc       = (float*)ws;                   // 16 floats
    int2*  obj_list  = (int2*)(ws + 64);             // 1024 * int2 (all slots written)
    int*   supp_list = (int*)(ws + 64 + NT * 8);     // 5120 ints  (all slots written)

    k_resolve<<<NT / 4, 256, 0, stream>>>(tg, acc, obj_list, supp_list);
    k_main<<<NBLK, 256, 0, stream>>>(x, tg, obj_list, supp_list, out, acc);
    k_final<<<1, 1, 0, stream>>>(acc, out + (size_t)CELLS * CH);
}